// Round 1
// baseline (409.117 us; speedup 1.0000x reference)
//
#include <hip/hip_runtime.h>

// ---------- types & helpers ----------
typedef __attribute__((ext_vector_type(8))) __bf16 bf16x8;
typedef __attribute__((ext_vector_type(4))) float f32x4;
typedef __attribute__((ext_vector_type(8))) ushort ushort8;

__device__ __forceinline__ ushort f2b(float f) {
  union { float f; uint u; } c; c.f = f;
  uint u = c.u;
  uint r = (u + 0x7fffu + ((u >> 16) & 1u)) >> 16;
  return (ushort)r;
}
__device__ __forceinline__ float b2f(ushort b) {
  union { uint u; float f; } c; c.u = ((uint)b) << 16;
  return c.f;
}

__device__ __forceinline__ float block_reduce_sum(float v, float* sm) {
#pragma unroll
  for (int off = 1; off < 64; off <<= 1) v += __shfl_xor(v, off);
  const int wave = threadIdx.x >> 6, lane = threadIdx.x & 63;
  __syncthreads();
  if (lane == 0) sm[wave] = v;
  __syncthreads();
  return sm[0] + sm[1] + sm[2] + sm[3];
}

// ---------- weight transpose + bf16 convert: Wt[n][k] = bf16(W[k][n]) ----------
__global__ __launch_bounds__(256) void wtrans_kernel(
    const float* __restrict__ W, ushort* __restrict__ Wt, int K, int N) {
  __shared__ float tile[32][33];
  const int n0 = blockIdx.x * 32, k0 = blockIdx.y * 32;
  const int tx = threadIdx.x, ty = threadIdx.y;  // block (32,8)
#pragma unroll
  for (int i = 0; i < 32; i += 8)
    tile[ty + i][tx] = W[(long)(k0 + ty + i) * N + n0 + tx];
  __syncthreads();
#pragma unroll
  for (int i = 0; i < 32; i += 8)
    Wt[(long)(n0 + ty + i) * K + k0 + tx] = f2b(tile[tx][ty + i]);
}

// ---------- LayerNorm (row of 1024) -> bf16 ----------
__global__ __launch_bounds__(256) void layernorm_kernel(
    const float* __restrict__ x, const float* __restrict__ g,
    const float* __restrict__ be, ushort* __restrict__ out) {
  __shared__ float sm[4];
  const long row = blockIdx.x;
  const float4 v = reinterpret_cast<const float4*>(x + row * 1024)[threadIdx.x];
  float s = v.x + v.y + v.z + v.w;
  s = block_reduce_sum(s, sm);
  const float mu = s * (1.0f / 1024.0f);
  const float dx = v.x - mu, dy = v.y - mu, dz = v.z - mu, dw = v.w - mu;
  float s2 = dx * dx + dy * dy + dz * dz + dw * dw;
  s2 = block_reduce_sum(s2, sm);
  const float rstd = rsqrtf(s2 * (1.0f / 1024.0f) + 1e-5f);
  const float4 gg = reinterpret_cast<const float4*>(g)[threadIdx.x];
  const float4 bb = reinterpret_cast<const float4*>(be)[threadIdx.x];
  ushort4 o;
  o.x = f2b(dx * rstd * gg.x + bb.x);
  o.y = f2b(dy * rstd * gg.y + bb.y);
  o.z = f2b(dz * rstd * gg.z + bb.z);
  o.w = f2b(dw * rstd * gg.w + bb.w);
  reinterpret_cast<ushort4*>(out + row * 1024)[threadIdx.x] = o;
}

// ---------- softmax over rows of 2048, in-place fp32 + bf16 copy ----------
__global__ __launch_bounds__(256) void softmax_kernel(
    float* __restrict__ s, ushort* __restrict__ wb) {
  __shared__ float sm[4];
  const long row = blockIdx.x;
  float4* r4 = reinterpret_cast<float4*>(s + row * 2048);
  float4 v0 = r4[threadIdx.x * 2];
  float4 v1 = r4[threadIdx.x * 2 + 1];
  float m = fmaxf(fmaxf(fmaxf(v0.x, v0.y), fmaxf(v0.z, v0.w)),
                  fmaxf(fmaxf(v1.x, v1.y), fmaxf(v1.z, v1.w)));
#pragma unroll
  for (int off = 1; off < 64; off <<= 1) m = fmaxf(m, __shfl_xor(m, off));
  const int wave = threadIdx.x >> 6, lane = threadIdx.x & 63;
  if (lane == 0) sm[wave] = m;
  __syncthreads();
  m = fmaxf(fmaxf(sm[0], sm[1]), fmaxf(sm[2], sm[3]));
  v0.x = expf(v0.x - m); v0.y = expf(v0.y - m);
  v0.z = expf(v0.z - m); v0.w = expf(v0.w - m);
  v1.x = expf(v1.x - m); v1.y = expf(v1.y - m);
  v1.z = expf(v1.z - m); v1.w = expf(v1.w - m);
  float sum = v0.x + v0.y + v0.z + v0.w + v1.x + v1.y + v1.z + v1.w;
  sum = block_reduce_sum(sum, sm);
  const float inv = 1.0f / sum;
  v0.x *= inv; v0.y *= inv; v0.z *= inv; v0.w *= inv;
  v1.x *= inv; v1.y *= inv; v1.z *= inv; v1.w *= inv;
  r4[threadIdx.x * 2] = v0;
  r4[threadIdx.x * 2 + 1] = v1;
  ushort8 o;
  o[0] = f2b(v0.x); o[1] = f2b(v0.y); o[2] = f2b(v0.z); o[3] = f2b(v0.w);
  o[4] = f2b(v1.x); o[5] = f2b(v1.y); o[6] = f2b(v1.z); o[7] = f2b(v1.w);
  *reinterpret_cast<ushort8*>(wb + row * 2048 + threadIdx.x * 8) = o;
}

// ---------- bf16 MFMA GEMM: C = A[M,K] * Bt[N,K]^T  (+ epilogue) ----------
#define EP_BF16 1
#define EP_F32 2
#define EP_BIAS 4
#define EP_RELU 8
#define EP_SCALE 16
#define EP_RESID 32
#define EP_TRANS 64

template <int FLAGS>
__global__ __launch_bounds__(256) void gemm_bt(
    const ushort* __restrict__ A, const ushort* __restrict__ Bt,
    float* __restrict__ Cf, ushort* __restrict__ Cb,
    const float* __restrict__ bias, const float* __restrict__ resid,
    int M, int N, int K, float scale, long sA, long sB, long sC) {
  A += (long)blockIdx.z * sA;
  Bt += (long)blockIdx.z * sB;
  const long coff = (long)blockIdx.z * sC;
  const int tileN = blockIdx.x * 128, tileM = blockIdx.y * 128;
  const int tid = threadIdx.x, lane = tid & 63;
  const int wm = tid >> 7, wn = (tid >> 6) & 1;
  __shared__ alignas(16) ushort As[128][40];
  __shared__ alignas(16) ushort Bs[128][40];
  f32x4 acc[4][4] = {};
  const int r0 = tid >> 2, k0 = (tid & 3) * 8;
  const int r1 = r0 + 64;
  for (int kk = 0; kk < K; kk += 32) {
    __syncthreads();
    *reinterpret_cast<int4*>(&As[r0][k0]) =
        *reinterpret_cast<const int4*>(&A[(long)(tileM + r0) * K + kk + k0]);
    *reinterpret_cast<int4*>(&As[r1][k0]) =
        *reinterpret_cast<const int4*>(&A[(long)(tileM + r1) * K + kk + k0]);
    *reinterpret_cast<int4*>(&Bs[r0][k0]) =
        *reinterpret_cast<const int4*>(&Bt[(long)(tileN + r0) * K + kk + k0]);
    *reinterpret_cast<int4*>(&Bs[r1][k0]) =
        *reinterpret_cast<const int4*>(&Bt[(long)(tileN + r1) * K + kk + k0]);
    __syncthreads();
    bf16x8 a[4], b[4];
#pragma unroll
    for (int m = 0; m < 4; ++m)
      a[m] = *reinterpret_cast<const bf16x8*>(
          &As[wm * 64 + m * 16 + (lane & 15)][(lane >> 4) * 8]);
#pragma unroll
    for (int n = 0; n < 4; ++n)
      b[n] = *reinterpret_cast<const bf16x8*>(
          &Bs[wn * 64 + n * 16 + (lane & 15)][(lane >> 4) * 8]);
#pragma unroll
    for (int m = 0; m < 4; ++m)
#pragma unroll
      for (int n = 0; n < 4; ++n)
        acc[m][n] = __builtin_amdgcn_mfma_f32_16x16x32_bf16(a[m], b[n], acc[m][n], 0, 0, 0);
  }
  const int row0 = tileM + wm * 64 + ((lane >> 4) << 2);
  const int col0 = tileN + wn * 64 + (lane & 15);
#pragma unroll
  for (int n = 0; n < 4; ++n) {
    const int col = col0 + n * 16;
    const float bv = (FLAGS & EP_BIAS) ? bias[col] : 0.0f;
#pragma unroll
    for (int m = 0; m < 4; ++m) {
#pragma unroll
      for (int i = 0; i < 4; ++i) {
        const int row = row0 + m * 16 + i;
        float v = acc[m][n][i];
        if (FLAGS & EP_SCALE) v *= scale;
        v += bv;
        if (FLAGS & EP_RELU) v = fmaxf(v, 0.0f);
        if (FLAGS & EP_RESID) v += resid[coff + (long)row * N + col];
        if (FLAGS & EP_F32) Cf[coff + (long)row * N + col] = v;
        if (FLAGS & EP_BF16) {
          if (FLAGS & EP_TRANS)
            Cb[coff + (long)col * M + row] = f2b(v);
          else
            Cb[coff + (long)row * N + col] = f2b(v);
        }
      }
    }
  }
}

// ---------- launch ----------
extern "C" void kernel_launch(void* const* d_in, const int* in_sizes, int n_in,
                              void* d_out, int out_size, void* d_ws, size_t ws_size,
                              hipStream_t stream) {
  const int B = 4, S = 2048, E = 1024, FFD = 1024;
  const long MS = (long)B * S;  // 8192
  const float* x   = (const float*)d_in[0];
  const float* Wq  = (const float*)d_in[1];
  const float* bq  = (const float*)d_in[2];
  const float* Wk  = (const float*)d_in[3];
  const float* bk  = (const float*)d_in[4];
  const float* Wv  = (const float*)d_in[5];
  const float* bv  = (const float*)d_in[6];
  const float* Wo  = (const float*)d_in[7];
  const float* bo  = (const float*)d_in[8];
  const float* W1  = (const float*)d_in[9];
  const float* b1  = (const float*)d_in[10];
  const float* W2  = (const float*)d_in[11];
  const float* b2  = (const float*)d_in[12];
  const float* g1  = (const float*)d_in[13];
  const float* be1 = (const float*)d_in[14];
  const float* g2  = (const float*)d_in[15];
  const float* be2 = (const float*)d_in[16];

  float* out  = (float*)d_out;           // [8192][1024]
  float* wout = out + MS * E;            // [4][2048][2048] fp32 scores -> softmax in place

  ushort* xnA = (ushort*)d_ws;           // xn (LN1) then xn2 (LN2)    [8192][1024] bf16
  ushort* qB  = xnA + MS * E;            // q  then pv                 [8192][1024] bf16
  ushort* kC  = qB + MS * E;             // k  then h (ffn1)           [8192][1024] bf16
  ushort* vTD = kC + MS * E;             // vT                     [4][1024][2048] bf16
  ushort* wE  = vTD + MS * E;            // w bf16                 [4][2048][2048] bf16
  float*  x2F = (float*)(wE + (long)B * S * S);  // x2 fp32         [8192][1024]
  ushort* wts = (ushort*)(x2F + MS * E);
  ushort* WqT = wts;                     // each [1024][1024] bf16, Wt[n][k]
  ushort* WkT = WqT + (long)E * E;
  ushort* WvT = WkT + (long)E * E;
  ushort* WoT = WvT + (long)E * E;
  ushort* W1T = WoT + (long)E * E;
  ushort* W2T = W1T + (long)E * FFD;

  dim3 tb(32, 8);
  dim3 tg(E / 32, E / 32);
  hipLaunchKernelGGL(wtrans_kernel, tg, tb, 0, stream, Wq, WqT, E, E);
  hipLaunchKernelGGL(wtrans_kernel, tg, tb, 0, stream, Wk, WkT, E, E);
  hipLaunchKernelGGL(wtrans_kernel, tg, tb, 0, stream, Wv, WvT, E, E);
  hipLaunchKernelGGL(wtrans_kernel, tg, tb, 0, stream, Wo, WoT, E, E);
  hipLaunchKernelGGL(wtrans_kernel, tg, tb, 0, stream, W1, W1T, E, FFD);
  hipLaunchKernelGGL(wtrans_kernel, tg, tb, 0, stream, W2, W2T, FFD, E);

  // LN1: x -> xn (bf16)
  hipLaunchKernelGGL(layernorm_kernel, dim3(MS), dim3(256), 0, stream, x, g1, be1, xnA);

  // q = xn @ Wq + bq  (bf16 out)
  hipLaunchKernelGGL((gemm_bt<EP_BF16 | EP_BIAS>), dim3(E / 128, MS / 128, 1), dim3(256), 0,
                     stream, xnA, WqT, (float*)nullptr, qB, bq, (const float*)nullptr,
                     (int)MS, E, E, 1.0f, 0L, 0L, 0L);
  // k = xn @ Wk + bk
  hipLaunchKernelGGL((gemm_bt<EP_BF16 | EP_BIAS>), dim3(E / 128, MS / 128, 1), dim3(256), 0,
                     stream, xnA, WkT, (float*)nullptr, kC, bk, (const float*)nullptr,
                     (int)MS, E, E, 1.0f, 0L, 0L, 0L);
  // vT[b][e][s] = (xn_b @ Wv + bv)^T  (batched, transposed bf16 out)
  hipLaunchKernelGGL((gemm_bt<EP_BF16 | EP_BIAS | EP_TRANS>), dim3(E / 128, S / 128, B),
                     dim3(256), 0, stream, xnA, WvT, (float*)nullptr, vTD, bv,
                     (const float*)nullptr, S, E, E, 1.0f, (long)S * E, 0L, (long)E * S);

  // scores = q_b @ k_b^T / 32  -> fp32 into d_out w-region
  hipLaunchKernelGGL((gemm_bt<EP_F32 | EP_SCALE>), dim3(S / 128, S / 128, B), dim3(256), 0,
                     stream, qB, kC, wout, (ushort*)nullptr, (const float*)nullptr,
                     (const float*)nullptr, S, S, E, 0.03125f, (long)S * E, (long)S * E,
                     (long)S * S);

  // softmax rows (in-place fp32 + bf16 copy)
  hipLaunchKernelGGL(softmax_kernel, dim3(B * S), dim3(256), 0, stream, wout, wE);

  // pv = w_b @ v_b  (A = w bf16, Bt = vT)  -> bf16 [8192][1024]
  hipLaunchKernelGGL((gemm_bt<EP_BF16>), dim3(E / 128, S / 128, B), dim3(256), 0, stream,
                     wE, vTD, (float*)nullptr, qB, (const float*)nullptr,
                     (const float*)nullptr, S, E, S, 1.0f, (long)S * S, (long)E * S,
                     (long)S * E);

  // x2 = x + pv @ Wo + bo  (fp32)
  hipLaunchKernelGGL((gemm_bt<EP_F32 | EP_BIAS | EP_RESID>), dim3(E / 128, MS / 128, 1),
                     dim3(256), 0, stream, qB, WoT, x2F, (ushort*)nullptr, bo, x,
                     (int)MS, E, E, 1.0f, 0L, 0L, 0L);

  // LN2: x2 -> xn2 (bf16)
  hipLaunchKernelGGL(layernorm_kernel, dim3(MS), dim3(256), 0, stream, x2F, g2, be2, xnA);

  // h = relu(xn2 @ W1 + b1)  (bf16)
  hipLaunchKernelGGL((gemm_bt<EP_BF16 | EP_BIAS | EP_RELU>), dim3(FFD / 128, MS / 128, 1),
                     dim3(256), 0, stream, xnA, W1T, (float*)nullptr, kC, b1,
                     (const float*)nullptr, (int)MS, FFD, E, 1.0f, 0L, 0L, 0L);

  // out = x2 + h @ W2 + b2  (fp32 -> d_out)
  hipLaunchKernelGGL((gemm_bt<EP_F32 | EP_BIAS | EP_RESID>), dim3(E / 128, MS / 128, 1),
                     dim3(256), 0, stream, kC, W2T, out, (ushort*)nullptr, b2, x2F,
                     (int)MS, E, FFD, 1.0f, 0L, 0L, 0L);
}

// Round 2
// 394.897 us; speedup vs baseline: 1.0360x; 1.0360x over previous
//
#include <hip/hip_runtime.h>

// ---------- types & helpers ----------
typedef __attribute__((ext_vector_type(8))) __bf16 bf16x8;
typedef __attribute__((ext_vector_type(4))) float f32x4;
typedef __attribute__((ext_vector_type(8))) ushort ushort8;

#define GLP(p) ((const __attribute__((address_space(1))) void*)(p))
#define LDP(p) ((__attribute__((address_space(3))) void*)(p))

__device__ __forceinline__ ushort f2b(float f) {
  union { float f; uint u; } c; c.f = f;
  uint u = c.u;
  uint r = (u + 0x7fffu + ((u >> 16) & 1u)) >> 16;
  return (ushort)r;
}

__device__ __forceinline__ float block_reduce_sum(float v, float* sm) {
#pragma unroll
  for (int off = 1; off < 64; off <<= 1) v += __shfl_xor(v, off);
  const int wave = threadIdx.x >> 6, lane = threadIdx.x & 63;
  __syncthreads();
  if (lane == 0) sm[wave] = v;
  __syncthreads();
  return sm[0] + sm[1] + sm[2] + sm[3];
}

// ---------- weight transpose + bf16 convert: Wt[n][k] = bf16(W[k][n]) ----------
__global__ __launch_bounds__(256) void wtrans_kernel(
    const float* __restrict__ W, ushort* __restrict__ Wt, int K, int N) {
  __shared__ float tile[32][33];
  const int n0 = blockIdx.x * 32, k0 = blockIdx.y * 32;
  const int tx = threadIdx.x, ty = threadIdx.y;  // block (32,8)
#pragma unroll
  for (int i = 0; i < 32; i += 8)
    tile[ty + i][tx] = W[(long)(k0 + ty + i) * N + n0 + tx];
  __syncthreads();
#pragma unroll
  for (int i = 0; i < 32; i += 8)
    Wt[(long)(n0 + ty + i) * K + k0 + tx] = f2b(tile[tx][ty + i]);
}

// ---------- LayerNorm (row of 1024) -> bf16 ----------
__global__ __launch_bounds__(256) void layernorm_kernel(
    const float* __restrict__ x, const float* __restrict__ g,
    const float* __restrict__ be, ushort* __restrict__ out) {
  __shared__ float sm[4];
  const long row = blockIdx.x;
  const float4 v = reinterpret_cast<const float4*>(x + row * 1024)[threadIdx.x];
  float s = v.x + v.y + v.z + v.w;
  s = block_reduce_sum(s, sm);
  const float mu = s * (1.0f / 1024.0f);
  const float dx = v.x - mu, dy = v.y - mu, dz = v.z - mu, dw = v.w - mu;
  float s2 = dx * dx + dy * dy + dz * dz + dw * dw;
  s2 = block_reduce_sum(s2, sm);
  const float rstd = rsqrtf(s2 * (1.0f / 1024.0f) + 1e-5f);
  const float4 gg = reinterpret_cast<const float4*>(g)[threadIdx.x];
  const float4 bb = reinterpret_cast<const float4*>(be)[threadIdx.x];
  ushort4 o;
  o.x = f2b(dx * rstd * gg.x + bb.x);
  o.y = f2b(dy * rstd * gg.y + bb.y);
  o.z = f2b(dz * rstd * gg.z + bb.z);
  o.w = f2b(dw * rstd * gg.w + bb.w);
  reinterpret_cast<ushort4*>(out + row * 1024)[threadIdx.x] = o;
}

// ---------- softmax over rows of 2048, in-place fp32 + bf16 copy ----------
__global__ __launch_bounds__(256) void softmax_kernel(
    float* __restrict__ s, ushort* __restrict__ wb) {
  __shared__ float sm[4];
  const long row = blockIdx.x;
  float4* r4 = reinterpret_cast<float4*>(s + row * 2048);
  float4 v0 = r4[threadIdx.x * 2];
  float4 v1 = r4[threadIdx.x * 2 + 1];
  float m = fmaxf(fmaxf(fmaxf(v0.x, v0.y), fmaxf(v0.z, v0.w)),
                  fmaxf(fmaxf(v1.x, v1.y), fmaxf(v1.z, v1.w)));
#pragma unroll
  for (int off = 1; off < 64; off <<= 1) m = fmaxf(m, __shfl_xor(m, off));
  const int wave = threadIdx.x >> 6, lane = threadIdx.x & 63;
  if (lane == 0) sm[wave] = m;
  __syncthreads();
  m = fmaxf(fmaxf(sm[0], sm[1]), fmaxf(sm[2], sm[3]));
  v0.x = expf(v0.x - m); v0.y = expf(v0.y - m);
  v0.z = expf(v0.z - m); v0.w = expf(v0.w - m);
  v1.x = expf(v1.x - m); v1.y = expf(v1.y - m);
  v1.z = expf(v1.z - m); v1.w = expf(v1.w - m);
  float sum = v0.x + v0.y + v0.z + v0.w + v1.x + v1.y + v1.z + v1.w;
  sum = block_reduce_sum(sum, sm);
  const float inv = 1.0f / sum;
  v0.x *= inv; v0.y *= inv; v0.z *= inv; v0.w *= inv;
  v1.x *= inv; v1.y *= inv; v1.z *= inv; v1.w *= inv;
  r4[threadIdx.x * 2] = v0;
  r4[threadIdx.x * 2 + 1] = v1;
  ushort8 o;
  o[0] = f2b(v0.x); o[1] = f2b(v0.y); o[2] = f2b(v0.z); o[3] = f2b(v0.w);
  o[4] = f2b(v1.x); o[5] = f2b(v1.y); o[6] = f2b(v1.z); o[7] = f2b(v1.w);
  *reinterpret_cast<ushort8*>(wb + row * 2048 + threadIdx.x * 8) = o;
}

// ---------- bf16 MFMA GEMM (m97 structure): C = A[M,K] * Bt[N,K]^T ----------
#define EP_BF16 1
#define EP_F32 2
#define EP_BIAS 4
#define EP_RELU 8
#define EP_SCALE 16
#define EP_RESID 32
#define EP_TRANS 64

template <int FLAGS>
__global__ __launch_bounds__(256) void gemm_bt(
    const ushort* __restrict__ A, const ushort* __restrict__ Bt,
    float* __restrict__ Cf, ushort* __restrict__ Cb,
    const float* __restrict__ bias, const float* __restrict__ resid,
    int M, int N, int K, float scale, long sA, long sB, long sC) {
  A += (long)blockIdx.z * sA;
  Bt += (long)blockIdx.z * sB;
  const long coff = (long)blockIdx.z * sC;
  const int tileN = blockIdx.x * 128, tileM = blockIdx.y * 128;
  const int tid = threadIdx.x, lane = tid & 63, wave = tid >> 6;
  const int wm = tid >> 7, wn = (tid >> 6) & 1;
  // UNPADDED linear LDS tiles: required by global_load_lds (wave-uniform base + lane*16B)
  __shared__ alignas(16) ushort As[128][32];
  __shared__ alignas(16) ushort Bs[128][32];
  f32x4 acc[4][4] = {};

  // staging: each wave covers rows [wave*32, wave*32+32) of A and Bt
  // instruction j (j=0,1): rows wave*32 + j*16 + (lane>>2), col (lane&3)*8
  const int srow = wave * 32 + (lane >> 2);
  const int scol = (lane & 3) * 8;
  const ushort* aP0 = A + (long)(tileM + srow) * K + scol;
  const ushort* aP1 = aP0 + 16L * K;
  const ushort* bP0 = Bt + (long)(tileN + srow) * K + scol;
  const ushort* bP1 = bP0 + 16L * K;
  ushort* lA0 = &As[wave * 32][0];
  ushort* lA1 = &As[wave * 32 + 16][0];
  ushort* lB0 = &Bs[wave * 32][0];
  ushort* lB1 = &Bs[wave * 32 + 16][0];

  for (int kk = 0; kk < K; kk += 32) {
    __syncthreads();  // previous iteration's ds_reads done before overwrite
    __builtin_amdgcn_global_load_lds(GLP(aP0 + kk), LDP(lA0), 16, 0, 0);
    __builtin_amdgcn_global_load_lds(GLP(aP1 + kk), LDP(lA1), 16, 0, 0);
    __builtin_amdgcn_global_load_lds(GLP(bP0 + kk), LDP(lB0), 16, 0, 0);
    __builtin_amdgcn_global_load_lds(GLP(bP1 + kk), LDP(lB1), 16, 0, 0);
    __syncthreads();  // compiler drains vmcnt(0) before barrier
    bf16x8 a[4], b[4];
#pragma unroll
    for (int m = 0; m < 4; ++m)
      a[m] = *reinterpret_cast<const bf16x8*>(
          &As[wm * 64 + m * 16 + (lane & 15)][(lane >> 4) * 8]);
#pragma unroll
    for (int n = 0; n < 4; ++n)
      b[n] = *reinterpret_cast<const bf16x8*>(
          &Bs[wn * 64 + n * 16 + (lane & 15)][(lane >> 4) * 8]);
#pragma unroll
    for (int m = 0; m < 4; ++m)
#pragma unroll
      for (int n = 0; n < 4; ++n)
        acc[m][n] = __builtin_amdgcn_mfma_f32_16x16x32_bf16(a[m], b[n], acc[m][n], 0, 0, 0);
  }
  const int row0 = tileM + wm * 64 + ((lane >> 4) << 2);
  const int col0 = tileN + wn * 64 + (lane & 15);
#pragma unroll
  for (int n = 0; n < 4; ++n) {
    const int col = col0 + n * 16;
    const float bv = (FLAGS & EP_BIAS) ? bias[col] : 0.0f;
#pragma unroll
    for (int m = 0; m < 4; ++m) {
#pragma unroll
      for (int i = 0; i < 4; ++i) {
        const int row = row0 + m * 16 + i;
        float v = acc[m][n][i];
        if (FLAGS & EP_SCALE) v *= scale;
        v += bv;
        if (FLAGS & EP_RELU) v = fmaxf(v, 0.0f);
        if (FLAGS & EP_RESID) v += resid[coff + (long)row * N + col];
        if (FLAGS & EP_F32) Cf[coff + (long)row * N + col] = v;
        if (FLAGS & EP_BF16) {
          if (FLAGS & EP_TRANS)
            Cb[coff + (long)col * M + row] = f2b(v);
          else
            Cb[coff + (long)row * N + col] = f2b(v);
        }
      }
    }
  }
}

// ---------- launch ----------
extern "C" void kernel_launch(void* const* d_in, const int* in_sizes, int n_in,
                              void* d_out, int out_size, void* d_ws, size_t ws_size,
                              hipStream_t stream) {
  const int B = 4, S = 2048, E = 1024, FFD = 1024;
  const long MS = (long)B * S;  // 8192
  const float* x   = (const float*)d_in[0];
  const float* Wq  = (const float*)d_in[1];
  const float* bq  = (const float*)d_in[2];
  const float* Wk  = (const float*)d_in[3];
  const float* bk  = (const float*)d_in[4];
  const float* Wv  = (const float*)d_in[5];
  const float* bv  = (const float*)d_in[6];
  const float* Wo  = (const float*)d_in[7];
  const float* bo  = (const float*)d_in[8];
  const float* W1  = (const float*)d_in[9];
  const float* b1  = (const float*)d_in[10];
  const float* W2  = (const float*)d_in[11];
  const float* b2  = (const float*)d_in[12];
  const float* g1  = (const float*)d_in[13];
  const float* be1 = (const float*)d_in[14];
  const float* g2  = (const float*)d_in[15];
  const float* be2 = (const float*)d_in[16];

  float* out  = (float*)d_out;           // [8192][1024]
  float* wout = out + MS * E;            // [4][2048][2048] fp32 scores -> softmax in place

  ushort* xnA = (ushort*)d_ws;           // xn (LN1) then xn2 (LN2)    [8192][1024] bf16
  ushort* qB  = xnA + MS * E;            // q  then pv                 [8192][1024] bf16
  ushort* kC  = qB + MS * E;             // k  then h (ffn1)           [8192][1024] bf16
  ushort* vTD = kC + MS * E;             // vT                     [4][1024][2048] bf16
  ushort* wE  = vTD + MS * E;            // w bf16                 [4][2048][2048] bf16
  float*  x2F = (float*)(wE + (long)B * S * S);  // x2 fp32         [8192][1024]
  ushort* wts = (ushort*)(x2F + MS * E);
  ushort* WqT = wts;                     // each [1024][1024] bf16, Wt[n][k]
  ushort* WkT = WqT + (long)E * E;
  ushort* WvT = WkT + (long)E * E;
  ushort* WoT = WvT + (long)E * E;
  ushort* W1T = WoT + (long)E * E;
  ushort* W2T = W1T + (long)E * FFD;

  dim3 tb(32, 8);
  dim3 tg(E / 32, E / 32);
  hipLaunchKernelGGL(wtrans_kernel, tg, tb, 0, stream, Wq, WqT, E, E);
  hipLaunchKernelGGL(wtrans_kernel, tg, tb, 0, stream, Wk, WkT, E, E);
  hipLaunchKernelGGL(wtrans_kernel, tg, tb, 0, stream, Wv, WvT, E, E);
  hipLaunchKernelGGL(wtrans_kernel, tg, tb, 0, stream, Wo, WoT, E, E);
  hipLaunchKernelGGL(wtrans_kernel, tg, tb, 0, stream, W1, W1T, E, FFD);
  hipLaunchKernelGGL(wtrans_kernel, tg, tb, 0, stream, W2, W2T, FFD, E);

  // LN1: x -> xn (bf16)
  hipLaunchKernelGGL(layernorm_kernel, dim3(MS), dim3(256), 0, stream, x, g1, be1, xnA);

  // q = xn @ Wq + bq  (bf16 out)
  hipLaunchKernelGGL((gemm_bt<EP_BF16 | EP_BIAS>), dim3(E / 128, MS / 128, 1), dim3(256), 0,
                     stream, xnA, WqT, (float*)nullptr, qB, bq, (const float*)nullptr,
                     (int)MS, E, E, 1.0f, 0L, 0L, 0L);
  // k = xn @ Wk + bk
  hipLaunchKernelGGL((gemm_bt<EP_BF16 | EP_BIAS>), dim3(E / 128, MS / 128, 1), dim3(256), 0,
                     stream, xnA, WkT, (float*)nullptr, kC, bk, (const float*)nullptr,
                     (int)MS, E, E, 1.0f, 0L, 0L, 0L);
  // vT[b][e][s] = (xn_b @ Wv + bv)^T  (batched, transposed bf16 out)
  hipLaunchKernelGGL((gemm_bt<EP_BF16 | EP_BIAS | EP_TRANS>), dim3(E / 128, S / 128, B),
                     dim3(256), 0, stream, xnA, WvT, (float*)nullptr, vTD, bv,
                     (const float*)nullptr, S, E, E, 1.0f, (long)S * E, 0L, (long)E * S);

  // scores = q_b @ k_b^T / 32  -> fp32 into d_out w-region
  hipLaunchKernelGGL((gemm_bt<EP_F32 | EP_SCALE>), dim3(S / 128, S / 128, B), dim3(256), 0,
                     stream, qB, kC, wout, (ushort*)nullptr, (const float*)nullptr,
                     (const float*)nullptr, S, S, E, 0.03125f, (long)S * E, (long)S * E,
                     (long)S * S);

  // softmax rows (in-place fp32 + bf16 copy)
  hipLaunchKernelGGL(softmax_kernel, dim3(B * S), dim3(256), 0, stream, wout, wE);

  // pv = w_b @ v_b  (A = w bf16, Bt = vT)  -> bf16 [8192][1024]
  hipLaunchKernelGGL((gemm_bt<EP_BF16>), dim3(E / 128, S / 128, B), dim3(256), 0, stream,
                     wE, vTD, (float*)nullptr, qB, (const float*)nullptr,
                     (const float*)nullptr, S, E, S, 1.0f, (long)S * S, (long)E * S,
                     (long)S * E);

  // x2 = x + pv @ Wo + bo  (fp32)
  hipLaunchKernelGGL((gemm_bt<EP_F32 | EP_BIAS | EP_RESID>), dim3(E / 128, MS / 128, 1),
                     dim3(256), 0, stream, qB, WoT, x2F, (ushort*)nullptr, bo, x,
                     (int)MS, E, E, 1.0f, 0L, 0L, 0L);

  // LN2: x2 -> xn2 (bf16)
  hipLaunchKernelGGL(layernorm_kernel, dim3(MS), dim3(256), 0, stream, x2F, g2, be2, xnA);

  // h = relu(xn2 @ W1 + b1)  (bf16)
  hipLaunchKernelGGL((gemm_bt<EP_BF16 | EP_BIAS | EP_RELU>), dim3(FFD / 128, MS / 128, 1),
                     dim3(256), 0, stream, xnA, W1T, (float*)nullptr, kC, b1,
                     (const float*)nullptr, (int)MS, FFD, E, 1.0f, 0L, 0L, 0L);

  // out = x2 + h @ W2 + b2  (fp32 -> d_out)
  hipLaunchKernelGGL((gemm_bt<EP_F32 | EP_BIAS | EP_RESID>), dim3(E / 128, MS / 128, 1),
                     dim3(256), 0, stream, kC, W2T, out, (ushort*)nullptr, b2, x2F,
                     (int)MS, E, FFD, 1.0f, 0L, 0L, 0L);
}

// Round 3
// 362.904 us; speedup vs baseline: 1.1273x; 1.0882x over previous
//
#include <hip/hip_runtime.h>

// ---------- types & helpers ----------
typedef __attribute__((ext_vector_type(8))) __bf16 bf16x8;
typedef __attribute__((ext_vector_type(4))) float f32x4;
typedef __attribute__((ext_vector_type(8))) ushort ushort8;

#define GLP(p) ((const __attribute__((address_space(1))) void*)(p))
#define LDP(p) ((__attribute__((address_space(3))) void*)(p))

__device__ __forceinline__ ushort f2b(float f) {
  union { float f; uint u; } c; c.f = f;
  uint u = c.u;
  uint r = (u + 0x7fffu + ((u >> 16) & 1u)) >> 16;
  return (ushort)r;
}

__device__ __forceinline__ float block_reduce_sum(float v, float* sm) {
#pragma unroll
  for (int off = 1; off < 64; off <<= 1) v += __shfl_xor(v, off);
  const int wave = threadIdx.x >> 6, lane = threadIdx.x & 63;
  __syncthreads();
  if (lane == 0) sm[wave] = v;
  __syncthreads();
  return sm[0] + sm[1] + sm[2] + sm[3];
}

// ---------- fused weight transpose + bf16 convert for all 6 weights ----------
__global__ __launch_bounds__(256) void wtrans6_kernel(
    const float* __restrict__ W0, const float* __restrict__ W1,
    const float* __restrict__ W2, const float* __restrict__ W3,
    const float* __restrict__ W4, const float* __restrict__ W5,
    ushort* __restrict__ T0, ushort* __restrict__ T1, ushort* __restrict__ T2,
    ushort* __restrict__ T3, ushort* __restrict__ T4, ushort* __restrict__ T5) {
  __shared__ float tile[32][33];
  const float* Ws[6] = {W0, W1, W2, W3, W4, W5};
  ushort* Ts[6] = {T0, T1, T2, T3, T4, T5};
  const float* W = Ws[blockIdx.z];
  ushort* Wt = Ts[blockIdx.z];
  const int K = 1024, N = 1024;
  const int n0 = blockIdx.x * 32, k0 = blockIdx.y * 32;
  const int tx = threadIdx.x, ty = threadIdx.y;  // block (32,8)
#pragma unroll
  for (int i = 0; i < 32; i += 8)
    tile[ty + i][tx] = W[(long)(k0 + ty + i) * N + n0 + tx];
  __syncthreads();
#pragma unroll
  for (int i = 0; i < 32; i += 8)
    Wt[(long)(n0 + ty + i) * K + k0 + tx] = f2b(tile[tx][ty + i]);
}

// ---------- LayerNorm (row of 1024) -> bf16 ----------
__global__ __launch_bounds__(256) void layernorm_kernel(
    const float* __restrict__ x, const float* __restrict__ g,
    const float* __restrict__ be, ushort* __restrict__ out) {
  __shared__ float sm[4];
  const long row = blockIdx.x;
  const float4 v = reinterpret_cast<const float4*>(x + row * 1024)[threadIdx.x];
  float s = v.x + v.y + v.z + v.w;
  s = block_reduce_sum(s, sm);
  const float mu = s * (1.0f / 1024.0f);
  const float dx = v.x - mu, dy = v.y - mu, dz = v.z - mu, dw = v.w - mu;
  float s2 = dx * dx + dy * dy + dz * dz + dw * dw;
  s2 = block_reduce_sum(s2, sm);
  const float rstd = rsqrtf(s2 * (1.0f / 1024.0f) + 1e-5f);
  const float4 gg = reinterpret_cast<const float4*>(g)[threadIdx.x];
  const float4 bb = reinterpret_cast<const float4*>(be)[threadIdx.x];
  ushort4 o;
  o.x = f2b(dx * rstd * gg.x + bb.x);
  o.y = f2b(dy * rstd * gg.y + bb.y);
  o.z = f2b(dz * rstd * gg.z + bb.z);
  o.w = f2b(dw * rstd * gg.w + bb.w);
  reinterpret_cast<ushort4*>(out + row * 1024)[threadIdx.x] = o;
}

// ---------- softmax over rows of 2048, in-place fp32 + bf16 copy ----------
__global__ __launch_bounds__(256) void softmax_kernel(
    float* __restrict__ s, ushort* __restrict__ wb) {
  __shared__ float sm[4];
  const long row = blockIdx.x;
  float4* r4 = reinterpret_cast<float4*>(s + row * 2048);
  float4 v0 = r4[threadIdx.x * 2];
  float4 v1 = r4[threadIdx.x * 2 + 1];
  float m = fmaxf(fmaxf(fmaxf(v0.x, v0.y), fmaxf(v0.z, v0.w)),
                  fmaxf(fmaxf(v1.x, v1.y), fmaxf(v1.z, v1.w)));
#pragma unroll
  for (int off = 1; off < 64; off <<= 1) m = fmaxf(m, __shfl_xor(m, off));
  const int wave = threadIdx.x >> 6, lane = threadIdx.x & 63;
  if (lane == 0) sm[wave] = m;
  __syncthreads();
  m = fmaxf(fmaxf(sm[0], sm[1]), fmaxf(sm[2], sm[3]));
  v0.x = expf(v0.x - m); v0.y = expf(v0.y - m);
  v0.z = expf(v0.z - m); v0.w = expf(v0.w - m);
  v1.x = expf(v1.x - m); v1.y = expf(v1.y - m);
  v1.z = expf(v1.z - m); v1.w = expf(v1.w - m);
  float sum = v0.x + v0.y + v0.z + v0.w + v1.x + v1.y + v1.z + v1.w;
  sum = block_reduce_sum(sum, sm);
  const float inv = 1.0f / sum;
  v0.x *= inv; v0.y *= inv; v0.z *= inv; v0.w *= inv;
  v1.x *= inv; v1.y *= inv; v1.z *= inv; v1.w *= inv;
  r4[threadIdx.x * 2] = v0;
  r4[threadIdx.x * 2 + 1] = v1;
  ushort8 o;
  o[0] = f2b(v0.x); o[1] = f2b(v0.y); o[2] = f2b(v0.z); o[3] = f2b(v0.w);
  o[4] = f2b(v1.x); o[5] = f2b(v1.y); o[6] = f2b(v1.z); o[7] = f2b(v1.w);
  *reinterpret_cast<ushort8*>(wb + row * 2048 + threadIdx.x * 8) = o;
}

// ---------- bf16 MFMA GEMM, 2-phase prefetch: C = A[M,K] * Bt[N,K]^T ----------
#define EP_BF16 1
#define EP_F32 2
#define EP_BIAS 4
#define EP_RELU 8
#define EP_SCALE 16
#define EP_RESID 32
#define EP_TRANS 64

template <int FLAGS>
__global__ __launch_bounds__(256) void gemm_bt(
    const ushort* __restrict__ A, const ushort* __restrict__ Bt,
    float* __restrict__ Cf, ushort* __restrict__ Cb,
    const float* __restrict__ bias, const float* __restrict__ resid,
    int M, int N, int K, float scale, long sA, long sB, long sC) {
  A += (long)blockIdx.z * sA;
  Bt += (long)blockIdx.z * sB;
  const long coff = (long)blockIdx.z * sC;
  const int tileN = blockIdx.x * 128, tileM = blockIdx.y * 128;
  const int tid = threadIdx.x, lane = tid & 63, wave = tid >> 6;
  const int wm = tid >> 7, wn = (tid >> 6) & 1;
  // UNPADDED linear LDS tiles (global_load_lds writes wave-uniform base + lane*16B).
  // Double-buffered: prefetch next K-tile while computing current.
  __shared__ alignas(16) ushort As[2][128][32];
  __shared__ alignas(16) ushort Bs[2][128][32];
  f32x4 acc[4][4] = {};

  // staging: each wave covers rows [wave*32, wave*32+32): lane l -> row wave*32+(l>>2), col (l&3)*8
  const int srow = wave * 32 + (lane >> 2);
  const int scol = (lane & 3) * 8;
  const ushort* aP0 = A + (long)(tileM + srow) * K + scol;
  const ushort* aP1 = aP0 + 16L * K;
  const ushort* bP0 = Bt + (long)(tileN + srow) * K + scol;
  const ushort* bP1 = bP0 + 16L * K;

#define STAGE(buf, kk)                                                                   \
  do {                                                                                   \
    __builtin_amdgcn_global_load_lds(GLP(aP0 + (kk)), LDP(&As[buf][wave * 32][0]), 16,   \
                                     0, 0);                                              \
    __builtin_amdgcn_global_load_lds(GLP(aP1 + (kk)), LDP(&As[buf][wave * 32 + 16][0]),  \
                                     16, 0, 0);                                          \
    __builtin_amdgcn_global_load_lds(GLP(bP0 + (kk)), LDP(&Bs[buf][wave * 32][0]), 16,   \
                                     0, 0);                                              \
    __builtin_amdgcn_global_load_lds(GLP(bP1 + (kk)), LDP(&Bs[buf][wave * 32 + 16][0]),  \
                                     16, 0, 0);                                          \
  } while (0)

  STAGE(0, 0);
  __syncthreads();  // buf0 ready (vmcnt drained by barrier)
  int cur = 0;
  for (int kk = 0; kk < K; kk += 32) {
    const int nxt = cur ^ 1;
    if (kk + 32 < K) STAGE(nxt, kk + 32);  // issue prefetch BEFORE compute
    bf16x8 a[4], b[4];
#pragma unroll
    for (int m = 0; m < 4; ++m)
      a[m] = *reinterpret_cast<const bf16x8*>(
          &As[cur][wm * 64 + m * 16 + (lane & 15)][(lane >> 4) * 8]);
#pragma unroll
    for (int n = 0; n < 4; ++n)
      b[n] = *reinterpret_cast<const bf16x8*>(
          &Bs[cur][wn * 64 + n * 16 + (lane & 15)][(lane >> 4) * 8]);
#pragma unroll
    for (int m = 0; m < 4; ++m)
#pragma unroll
      for (int n = 0; n < 4; ++n)
        acc[m][n] = __builtin_amdgcn_mfma_f32_16x16x32_bf16(a[m], b[n], acc[m][n], 0, 0, 0);
    __syncthreads();  // one barrier/K-step: drains prefetch + fragment reads
    cur = nxt;
  }
#undef STAGE

  const int row0 = tileM + wm * 64 + ((lane >> 4) << 2);
  const int col0 = tileN + wn * 64 + (lane & 15);
#pragma unroll
  for (int n = 0; n < 4; ++n) {
    const int col = col0 + n * 16;
    const float bv = (FLAGS & EP_BIAS) ? bias[col] : 0.0f;
#pragma unroll
    for (int m = 0; m < 4; ++m) {
#pragma unroll
      for (int i = 0; i < 4; ++i) {
        const int row = row0 + m * 16 + i;
        float v = acc[m][n][i];
        if (FLAGS & EP_SCALE) v *= scale;
        v += bv;
        if (FLAGS & EP_RELU) v = fmaxf(v, 0.0f);
        if (FLAGS & EP_RESID) v += resid[coff + (long)row * N + col];
        if (FLAGS & EP_F32) Cf[coff + (long)row * N + col] = v;
        if (FLAGS & EP_BF16) {
          if (FLAGS & EP_TRANS)
            Cb[coff + (long)col * M + row] = f2b(v);
          else
            Cb[coff + (long)row * N + col] = f2b(v);
        }
      }
    }
  }
}

// ---------- launch ----------
extern "C" void kernel_launch(void* const* d_in, const int* in_sizes, int n_in,
                              void* d_out, int out_size, void* d_ws, size_t ws_size,
                              hipStream_t stream) {
  const int B = 4, S = 2048, E = 1024, FFD = 1024;
  const long MS = (long)B * S;  // 8192
  const float* x   = (const float*)d_in[0];
  const float* Wq  = (const float*)d_in[1];
  const float* bq  = (const float*)d_in[2];
  const float* Wk  = (const float*)d_in[3];
  const float* bk  = (const float*)d_in[4];
  const float* Wv  = (const float*)d_in[5];
  const float* bv  = (const float*)d_in[6];
  const float* Wo  = (const float*)d_in[7];
  const float* bo  = (const float*)d_in[8];
  const float* W1  = (const float*)d_in[9];
  const float* b1  = (const float*)d_in[10];
  const float* W2  = (const float*)d_in[11];
  const float* b2  = (const float*)d_in[12];
  const float* g1  = (const float*)d_in[13];
  const float* be1 = (const float*)d_in[14];
  const float* g2  = (const float*)d_in[15];
  const float* be2 = (const float*)d_in[16];

  float* out  = (float*)d_out;           // [8192][1024]
  float* wout = out + MS * E;            // [4][2048][2048] fp32 scores -> softmax in place

  ushort* xnA = (ushort*)d_ws;           // xn (LN1) then xn2 (LN2)    [8192][1024] bf16
  ushort* qB  = xnA + MS * E;            // q  then pv                 [8192][1024] bf16
  ushort* kC  = qB + MS * E;             // k  then h (ffn1)           [8192][1024] bf16
  ushort* vTD = kC + MS * E;             // vT                     [4][1024][2048] bf16
  ushort* wE  = vTD + MS * E;            // w bf16                 [4][2048][2048] bf16
  float*  x2F = (float*)(wE + (long)B * S * S);  // x2 fp32         [8192][1024]
  ushort* wts = (ushort*)(x2F + MS * E);
  ushort* WqT = wts;                     // each [1024][1024] bf16, Wt[n][k]
  ushort* WkT = WqT + (long)E * E;
  ushort* WvT = WkT + (long)E * E;
  ushort* WoT = WvT + (long)E * E;
  ushort* W1T = WoT + (long)E * E;
  ushort* W2T = W1T + (long)E * FFD;

  // all 6 weight transposes in one launch
  hipLaunchKernelGGL(wtrans6_kernel, dim3(E / 32, E / 32, 6), dim3(32, 8), 0, stream,
                     Wq, Wk, Wv, Wo, W1, W2, WqT, WkT, WvT, WoT, W1T, W2T);

  // LN1: x -> xn (bf16)
  hipLaunchKernelGGL(layernorm_kernel, dim3(MS), dim3(256), 0, stream, x, g1, be1, xnA);

  // q = xn @ Wq + bq  (bf16 out)
  hipLaunchKernelGGL((gemm_bt<EP_BF16 | EP_BIAS>), dim3(E / 128, MS / 128, 1), dim3(256), 0,
                     stream, xnA, WqT, (float*)nullptr, qB, bq, (const float*)nullptr,
                     (int)MS, E, E, 1.0f, 0L, 0L, 0L);
  // k = xn @ Wk + bk
  hipLaunchKernelGGL((gemm_bt<EP_BF16 | EP_BIAS>), dim3(E / 128, MS / 128, 1), dim3(256), 0,
                     stream, xnA, WkT, (float*)nullptr, kC, bk, (const float*)nullptr,
                     (int)MS, E, E, 1.0f, 0L, 0L, 0L);
  // vT[b][e][s] = (xn_b @ Wv + bv)^T  (batched, transposed bf16 out)
  hipLaunchKernelGGL((gemm_bt<EP_BF16 | EP_BIAS | EP_TRANS>), dim3(E / 128, S / 128, B),
                     dim3(256), 0, stream, xnA, WvT, (float*)nullptr, vTD, bv,
                     (const float*)nullptr, S, E, E, 1.0f, (long)S * E, 0L, (long)E * S);

  // scores = q_b @ k_b^T / 32  -> fp32 into d_out w-region
  hipLaunchKernelGGL((gemm_bt<EP_F32 | EP_SCALE>), dim3(S / 128, S / 128, B), dim3(256), 0,
                     stream, qB, kC, wout, (ushort*)nullptr, (const float*)nullptr,
                     (const float*)nullptr, S, S, E, 0.03125f, (long)S * E, (long)S * E,
                     (long)S * S);

  // softmax rows (in-place fp32 + bf16 copy)
  hipLaunchKernelGGL(softmax_kernel, dim3(B * S), dim3(256), 0, stream, wout, wE);

  // pv = w_b @ v_b  (A = w bf16, Bt = vT)  -> bf16 [8192][1024]
  hipLaunchKernelGGL((gemm_bt<EP_BF16>), dim3(E / 128, S / 128, B), dim3(256), 0, stream,
                     wE, vTD, (float*)nullptr, qB, (const float*)nullptr,
                     (const float*)nullptr, S, E, S, 1.0f, (long)S * S, (long)E * S,
                     (long)S * E);

  // x2 = x + pv @ Wo + bo  (fp32)
  hipLaunchKernelGGL((gemm_bt<EP_F32 | EP_BIAS | EP_RESID>), dim3(E / 128, MS / 128, 1),
                     dim3(256), 0, stream, qB, WoT, x2F, (ushort*)nullptr, bo, x,
                     (int)MS, E, E, 1.0f, 0L, 0L, 0L);

  // LN2: x2 -> xn2 (bf16)
  hipLaunchKernelGGL(layernorm_kernel, dim3(MS), dim3(256), 0, stream, x2F, g2, be2, xnA);

  // h = relu(xn2 @ W1 + b1)  (bf16)
  hipLaunchKernelGGL((gemm_bt<EP_BF16 | EP_BIAS | EP_RELU>), dim3(FFD / 128, MS / 128, 1),
                     dim3(256), 0, stream, xnA, W1T, (float*)nullptr, kC, b1,
                     (const float*)nullptr, (int)MS, FFD, E, 1.0f, 0L, 0L, 0L);

  // out = x2 + h @ W2 + b2  (fp32 -> d_out)
  hipLaunchKernelGGL((gemm_bt<EP_F32 | EP_BIAS | EP_RESID>), dim3(E / 128, MS / 128, 1),
                     dim3(256), 0, stream, kC, W2T, out, (ushort*)nullptr, b2, x2F,
                     (int)MS, E, FFD, 1.0f, 0L, 0L, 0L);
}